// Round 4
// baseline (300.828 us; speedup 1.0000x reference)
//
#include <hip/hip_runtime.h>
#include <hip/hip_bf16.h>

// Problem constants
#define NB   16      // batch
#define NC   256     // C_FEAT
#define HF   80
#define WF   80
#define NPIX 6400    // HF*WF
#define ND   64      // C_ILL
#define NK   3       // experts
#define HZ   40
#define WZ   40
#define NKC  7       // 224/32 k-chunks (192 kd + 3 bias + pad)
#define ZROW 232     // zp LDS row stride (bf16 elems): 232*2=464 B, 16B-aligned,
                     // pix*116 mod 32 has period 8 -> <=2-way bank alias (free, m136)
// Swizzled A: [g=8][kc=7][mt=4][lane=64][8] bf16; g = 32-channel group, cbase=g*32
#define A_G_STRIDE  (NKC * 4 * 512)             // 14336 elem per g

typedef __bf16 bf16;
typedef __bf16 bf16x8 __attribute__((ext_vector_type(8)));
typedef float  floatx4 __attribute__((ext_vector_type(4)));

// ---------------------------------------------------------------------------
// Kernel 1: pack expert weights into swizzled A (unchanged from R3).
// Chunk i = ((g*7+kc)*4+mt)*64 + lane; lane=(q,l15); cbase = g*32.
// mt<2 -> gamma c = cbase+(mt&1)*16+l15 ; mt>=2 -> beta, same c formula.
// kd0 = kc*32+q*8; kd<192 = W[k][c][d], kd 192..194 = bias, else 0.
// ---------------------------------------------------------------------------
__global__ __launch_bounds__(256) void pack_A_kernel(
    const float* __restrict__ Wg, const float* __restrict__ bg,
    const float* __restrict__ Wb, const float* __restrict__ bb,
    bf16* __restrict__ A2)
{
    int i = blockIdx.x * 256 + threadIdx.x;   // 0 .. 14335
    int lane = i & 63;
    int j2 = i >> 6;           // 0..223
    int mt = j2 & 3;
    int j3 = j2 >> 2;          // 0..55
    int kc = j3 % 7;
    int g  = j3 / 7;           // 0..7
    int l15 = lane & 15, q = lane >> 4;
    int c = g * 32 + (mt & 1) * 16 + l15;
    const float* W    = (mt >= 2) ? Wb : Wg;
    const float* bias = (mt >= 2) ? bb : bg;
    int kd0 = kc * 32 + q * 8;

    bf16x8 v;
    if (kd0 < NK * ND) {
        int k = kd0 >> 6, d = kd0 & 63;
        const float* src = W + ((size_t)k * NC + c) * ND + d;
        #pragma unroll
        for (int j = 0; j < 8; ++j) v[j] = (bf16)src[j];
    } else if (kd0 == NK * ND) {
        #pragma unroll
        for (int j = 0; j < 8; ++j) v[j] = (bf16)0.0f;
        v[0] = (bf16)bias[0 * NC + c];
        v[1] = (bf16)bias[1 * NC + c];
        v[2] = (bf16)bias[2 * NC + c];
    } else {
        #pragma unroll
        for (int j = 0; j < 8; ++j) v[j] = (bf16)0.0f;
    }
    *reinterpret_cast<bf16x8*>(A2 + (size_t)i * 8) = v;
}

// ---------------------------------------------------------------------------
// Kernel 2 (fused): per (c-half ct, row h, batch b):
//   stage 1: bilinear-upsample P row -> p_up LDS; zero zp bias region
//   stage 2: bilinear-upsample Z row, multiply by p_up, write zp LDS (bf16)
//   K-loop : A-frags = coalesced 1KB global loads (L2-hot packed A),
//            B-frags = single ds_read_b128 from zp
//   epilogue: out = feat*(1+gamma)+beta, fp32
// Replaces R3's build_zp kernel + 46MB ZP write + 46MB re-read.
// ---------------------------------------------------------------------------
__global__ __launch_bounds__(256) void gemm_film_fused(
    const bf16* __restrict__ A2, const float* __restrict__ Z,
    const float* __restrict__ P, const float* __restrict__ feat,
    float* __restrict__ out)
{
    __shared__ bf16  zp[WF * ZROW];      // 37120 B
    __shared__ float p_up[WF][NK];       // 960 B

    const int ct = blockIdx.x;   // 0..1 (c-half)
    const int h  = blockIdx.y;   // 0..79
    const int b  = blockIdx.z;   // 0..15
    const int t    = threadIdx.x;
    const int lane = t & 63;
    const int wv   = t >> 6;
    const int l15  = lane & 15;
    const int q    = lane >> 4;

    // vertical source coords (uniform across block)
    float srch = 0.5f * (float)h - 0.25f;
    float flh  = floorf(srch);
    float fh   = srch - flh;
    int h0 = max((int)flh, 0);
    int h1 = min((int)flh + 1, HZ - 1);

    // ---- stage 1: zero zp[w][192..223] (u32 writes) + p_up row ----
    {
        unsigned* zpu = (unsigned*)zp;   // elem offset w*232+192 -> u32 offset w*116+96
        #pragma unroll
        for (int i = t; i < WF * 16; i += 256) {
            int w = i >> 4, j = i & 15;
            zpu[w * 116 + 96 + j] = 0u;
        }
    }
    if (t < WF * NK) {
        int w = t / NK;
        int k = t - w * NK;
        float srcw = 0.5f * (float)w - 0.25f;
        float flw  = floorf(srcw);
        float fw   = srcw - flw;
        int w0 = max((int)flw, 0);
        int w1 = min((int)flw + 1, WZ - 1);
        const float* Pr = P + (size_t)(b * NK + k) * (HZ * WZ);
        float p00 = Pr[h0 * WZ + w0], p01 = Pr[h0 * WZ + w1];
        float p10 = Pr[h1 * WZ + w0], p11 = Pr[h1 * WZ + w1];
        float pi0 = p00 + fw * (p01 - p00);
        float pi1 = p10 + fw * (p11 - p10);
        p_up[w][k] = pi0 + fh * (pi1 - pi0);
    }
    __syncthreads();

    // ---- stage 2: bias entries + z entries ----
    if (t < WF * NK) {
        int w = t / NK;
        int k = t - w * NK;
        zp[w * ZROW + NK * ND + k] = (bf16)p_up[w][k];
    }
    #pragma unroll 4
    for (int i = 0; i < 20; ++i) {
        int e = t + 256 * i;          // < 5120
        int d = e / WF;
        int w = e - d * WF;
        float srcw = 0.5f * (float)w - 0.25f;
        float flw  = floorf(srcw);
        float fw   = srcw - flw;
        int w0 = max((int)flw, 0);
        int w1 = min((int)flw + 1, WZ - 1);
        const float* Zr = Z + (size_t)(b * ND + d) * (HZ * WZ);
        float z00 = Zr[h0 * WZ + w0], z01 = Zr[h0 * WZ + w1];
        float z10 = Zr[h1 * WZ + w0], z11 = Zr[h1 * WZ + w1];
        float zi0 = z00 + fw * (z01 - z00);
        float zi1 = z10 + fw * (z11 - z10);
        float zv  = zi0 + fh * (zi1 - zi0);
        bf16* row = zp + w * ZROW;
        row[d]            = (bf16)(p_up[w][0] * zv);
        row[ND + d]       = (bf16)(p_up[w][1] * zv);
        row[2 * ND + d]   = (bf16)(p_up[w][2] * zv);
    }
    __syncthreads();

    // ---- K-loop: wave wv owns 32 channels (gamma+beta), all 80 pixels ----
    const int g = ct * 4 + wv;       // A tile id, cbase = g*32
    const bf16* aptr = A2 + (size_t)g * A_G_STRIDE + (size_t)lane * 8;

    floatx4 acc[4][5] = {};  // [mt: 0,1 gamma / 2,3 beta][nt: 5 x 16 px]

    for (int kc = 0; kc < NKC; ++kc) {
        bf16x8 af[4];
        #pragma unroll
        for (int mt = 0; mt < 4; ++mt)
            af[mt] = *reinterpret_cast<const bf16x8*>(aptr + mt * 512);
        aptr += 4 * 512;
        const int kd0 = kc * 32 + q * 8;
        #pragma unroll
        for (int nt = 0; nt < 5; ++nt) {
            bf16x8 bfr = *reinterpret_cast<const bf16x8*>(
                zp + (nt * 16 + l15) * ZROW + kd0);
            #pragma unroll
            for (int mt = 0; mt < 4; ++mt)
                acc[mt][nt] = __builtin_amdgcn_mfma_f32_16x16x32_bf16(
                    af[mt], bfr, acc[mt][nt], 0, 0, 0);
        }
    }

    // ---- fused FiLM epilogue: out = feat*(1+gamma)+beta (fp32) ----
    const int cbase = g * 32;
    const size_t imgbase = (size_t)b * NC * NPIX + (size_t)h * WF;
    #pragma unroll
    for (int mt = 0; mt < 2; ++mt) {
        #pragma unroll
        for (int r = 0; r < 4; ++r) {
            int c = cbase + mt * 16 + q * 4 + r;
            const float* frow = feat + imgbase + (size_t)c * NPIX;
            float*       orow = out  + imgbase + (size_t)c * NPIX;
            #pragma unroll
            for (int nt = 0; nt < 5; ++nt) {
                int pix = nt * 16 + l15;
                float ga = acc[mt][nt][r];
                float be = acc[mt + 2][nt][r];
                float f  = frow[pix];
                orow[pix] = f * (1.0f + ga) + be;
            }
        }
    }
}

// ---------------------------------------------------------------------------
extern "C" void kernel_launch(void* const* d_in, const int* in_sizes, int n_in,
                              void* d_out, int out_size, void* d_ws, size_t ws_size,
                              hipStream_t stream)
{
    (void)in_sizes; (void)n_in; (void)out_size; (void)ws_size;
    const float* feat = (const float*)d_in[0];
    const float* Z    = (const float*)d_in[1];
    const float* P    = (const float*)d_in[2];
    const float* Wg   = (const float*)d_in[3];
    const float* bg   = (const float*)d_in[4];
    const float* Wb   = (const float*)d_in[5];
    const float* bb   = (const float*)d_in[6];

    bf16* Apk = (bf16*)d_ws;          // 14336*8*2 = 229,376 B
    float* out = (float*)d_out;

    pack_A_kernel<<<56, 256, 0, stream>>>(Wg, bg, Wb, bb, Apk);

    dim3 grid(2, HF, NB);
    gemm_film_fused<<<grid, 256, 0, stream>>>(Apk, Z, P, feat, out);
}